// Round 5
// baseline (2118.120 us; speedup 1.0000x reference)
//
#include <hip/hip_runtime.h>
#include <stdint.h>

// HeteroscedasticSoftmax: out = mean_{s<100} softmax(logits + eps_s * exp(log_std), axis=C)
// eps reproduces jax.random.normal under the partitionable threefry scheme (verified):
//   key_s  = threefry2x32((0,1), (0, s))
//   bits_j = w0 ^ w1 of threefry2x32(key_s, (0, j)), j = flat element index
//   u from top 23 bits; eps = sqrt2*erfinv(u) (coeff-folded, log2-domain central poly)
//
// R6 (resubmit; previous round was an infra failure, no HW signal).
// Scheduling-region attack, numerics bit-identical to verified R5.
// R5 post-mortem: real VALU busy ~56% (VALUBusy=112 via the gfx94x SIMD-16 formula),
// unchanged from 4 -> 6.8 waves/SIMD. Cause theory: the per-draw branch in bits_to_eps
// splits the unrolled c-loop into ~19 basic blocks; LLVM schedules per-BB, so the 19
// serially-dependent threefry chains (75% of all instructions, ~75% solo fill) can
// never interleave with each other, and each v_log's trans latency is exposed.
// Restructure:
//  - Phase 1 (ONE giant branch-free BB): all 19 chains + u + v_log interleavable;
//    stores u[19], t[19].
//  - Phase 2: branchy erfinv polys (predicate on t, == R2's original form) + z[19].
//  - Parallel chain init: x0 = jbase + (k0+k1+c*HW) [SALU const], x1 = jbase + (k1+c*HW)
//    -- same mod-2^32 value as x0=k0+x1, but breaks the init dependency.
//  - 1-deep skey prefetch hides the per-sample ds_read_b64 latency.

#define NCH    19
#define HW     65536
#define NSAMP  100

__device__ __forceinline__ uint32_t rotl(uint32_t x, uint32_t r) {
  return __builtin_amdgcn_alignbit(x, x, 32u - r);
}

__device__ __forceinline__ void tf2x32_full(uint32_t k0, uint32_t k1,
                                            uint32_t x0, uint32_t x1,
                                            uint32_t& o0, uint32_t& o1) {
  const uint32_t k2 = k0 ^ k1 ^ 0x1BD11BDAu;
#define TFR(r) { x0 += x1; x1 = rotl(x1, r) ^ x0; }
  x0 += k0; x1 += k1;
  TFR(13u) TFR(15u) TFR(26u) TFR(6u)
  x0 += k1; x1 += k2 + 1u;
  TFR(17u) TFR(29u) TFR(16u) TFR(24u)
  x0 += k2; x1 += k0 + 2u;
  TFR(13u) TFR(15u) TFR(26u) TFR(6u)
  x0 += k0; x1 += k1 + 3u;
  TFR(17u) TFR(29u) TFR(16u) TFR(24u)
  x0 += k1; x1 += k2 + 4u;
  TFR(13u) TFR(15u) TFR(26u) TFR(6u)
  x0 += k2; x1 += k0 + 5u;
#undef TFR
  o0 = x0; o1 = x1;
}

// Hot-path threefry given both initial regs (x0 = counter + k0 + k1-part already
// folded; x1 = counter + k1-part). Identical arithmetic to the verified form:
// old x0 = k0 + x1 = jbase + (k0 + k1 + c*HW). Returns o0 ^ o1.
__device__ __forceinline__ uint32_t tf_fold_xy(uint32_t k0, uint32_t k1, uint32_t k2,
                                               uint32_t x0, uint32_t x1) {
  x1 = rotl(x1, 13u) ^ x0;
  x0 += x1; x1 = rotl(x1, 15u) ^ x0;
  x0 += x1; x1 = rotl(x1, 26u) ^ x0;
  x0 += x1; x1 = rotl(x1,  6u) ^ x0;
  x1 += k2 + 1u;
  x0 = x0 + k1 + x1; x1 = rotl(x1, 17u) ^ x0;
  x0 += x1; x1 = rotl(x1, 29u) ^ x0;
  x0 += x1; x1 = rotl(x1, 16u) ^ x0;
  x0 += x1; x1 = rotl(x1, 24u) ^ x0;
  x1 += k0 + 2u;
  x0 = x0 + k2 + x1; x1 = rotl(x1, 13u) ^ x0;
  x0 += x1; x1 = rotl(x1, 15u) ^ x0;
  x0 += x1; x1 = rotl(x1, 26u) ^ x0;
  x0 += x1; x1 = rotl(x1,  6u) ^ x0;
  x1 += k1 + 3u;
  x0 = x0 + k0 + x1; x1 = rotl(x1, 17u) ^ x0;
  x0 += x1; x1 = rotl(x1, 29u) ^ x0;
  x0 += x1; x1 = rotl(x1, 16u) ^ x0;
  x0 += x1; x1 = rotl(x1, 24u) ^ x0;
  x1 += k2 + 4u;
  x0 = x0 + k1 + x1; x1 = rotl(x1, 13u) ^ x0;
  x0 += x1; x1 = rotl(x1, 15u) ^ x0;
  x0 += x1; x1 = rotl(x1, 26u) ^ x0;
  x0 += x1; x1 = rotl(x1,  6u) ^ x0;
  return (x0 + k2) ^ (x1 + k0 + 5u);
}

__device__ __forceinline__ float max3(float a, float b, float c) {
  return fmaxf(fmaxf(a, b), c);   // clang fuses to v_max3_f32
}

__global__ __launch_bounds__(256, 4)
void HeteroscedasticSoftmax_kernel(const float* __restrict__ in,
                                   float* __restrict__ out) {
  __shared__ uint2 skey[NSAMP];

  const int t = threadIdx.x;
  if (t < NSAMP) {
    uint32_t a, b;
    tf2x32_full(0u, 1u, 0u, (uint32_t)t, a, b);
    skey[t] = make_uint2(a, b);
  }

  const int gid = blockIdx.x * 256 + t;    // one pixel per thread
  const int b_  = gid >> 16;
  const int hw  = gid & 65535;

  const float L2E = 1.4426950408889634f;
  const float* pin = in + (size_t)b_ * (2 * NCH * HW) + hw;
  float lgE[NCH], sdE[NCH], acc[NCH];
#pragma unroll
  for (int c = 0; c < NCH; ++c) {
    const float lg = pin[c * HW];
    const float ls = pin[(NCH + c) * HW];
    lgE[c] = lg * L2E;
    sdE[c] = __expf(ls) * L2E;
    acc[c] = 0.0f;
  }
  __syncthreads();

  const uint32_t jbase = (uint32_t)(b_ * NCH) * (uint32_t)HW + (uint32_t)hw;

  uint2 kk = skey[0];   // after barrier; 1-deep prefetch below

#pragma unroll 1
  for (int s = 0; s < NSAMP; ++s) {
    const uint2 kknext = skey[(s + 1 < NSAMP) ? s + 1 : 0];  // issue early, consumed next iter
    const uint32_t k0 = __builtin_amdgcn_readfirstlane(kk.x);
    const uint32_t k1 = __builtin_amdgcn_readfirstlane(kk.y);
    const uint32_t k2 = k0 ^ k1 ^ 0x1BD11BDAu;

    // ---- Phase 1: ONE branch-free BB -- 19 independent threefry chains + u + log.
    float u_[NCH], t_[NCH];
#pragma unroll
    for (int c = 0; c < NCH; ++c) {
      const uint32_t k1c  = k1 + (uint32_t)(c * HW);   // SALU (wave-uniform)
      const uint32_t k01c = k0 + k1c;                  // SALU (wave-uniform)
      const uint32_t bits = tf_fold_xy(k0, k1, k2, jbase + k01c, jbase + k1c);
      // y = bitcast(0x40000000 | (bits>>9)) in [2,4) == 2x
      const float y = __uint_as_float(__builtin_amdgcn_alignbit(0x80u, bits, 9u));
      float u = y - 3.0f;                  // exact (Sterbenz); in [-1.0, 0.99999976]
      u = fmaxf(u, -0.99999994f);          // REQUIRED: u=-1.0 at bits>>9==0 -> log2(0) -> NaN
      u_[c] = u;
      t_[c] = __builtin_amdgcn_logf(fmaf(-u, u, 1.0f));   // log2(1-u^2) <= 0
    }

    // ---- Phase 2: branchy erfinv polys (sqrt(2)*erfinv, coeff-folded) + z.
    float z[NCH];
#pragma unroll
    for (int c = 0; c < NCH; ++c) {
      const float u = u_[c];
      const float tt = t_[c];
      float p;
      if (tt > -7.2135401f) {       // central branch: w = -ln2*t < 5
        float tw = tt + 3.6067376f; // t - beta
        p = 2.1176667e-09f;
        p = fmaf(p, tw, -3.7319753e-08f);
        p = fmaf(p, tw, -5.5262077e-07f);
        p = fmaf(p, tw, 9.9370361e-07f);
        p = fmaf(p, tw, 7.1355918e-05f);
        p = fmaf(p, tw, 5.9046852e-04f);
        p = fmaf(p, tw, -2.8386612e-03f);
        p = fmaf(p, tw, -2.4177230e-01f);
        p = fmaf(p, tw, 2.1233141e+00f);
      } else {                      // tail (rare): reconstruct w
        float w = -0.69314718f * tt;
        w = __fsqrt_rn(w) - 3.0f;
        p = -2.8314594e-04f;
        p = fmaf(p, w, 1.4276565e-04f);
        p = fmaf(p, w, 1.9082604e-03f);
        p = fmaf(p, w, -5.1950124e-03f);
        p = fmaf(p, w, 8.1168916e-03f);
        p = fmaf(p, w, -1.0779791e-02f);
        p = fmaf(p, w, 1.3348577e-02f);
        p = fmaf(p, w, 1.4165810e+00f);
        p = fmaf(p, w, 4.0064324e+00f);
      }
      const float eps = p * u;
      z[c] = fmaf(eps, sdE[c], lgE[c]);   // (lg + eps*sd) * log2(e)
    }

    // ---- softmax over 19 channels
    float a0 = max3(z[0],  z[1],  z[2]);
    float a1 = max3(z[3],  z[4],  z[5]);
    float a2 = max3(z[6],  z[7],  z[8]);
    float a3 = max3(z[9],  z[10], z[11]);
    float a4 = max3(z[12], z[13], z[14]);
    float a5 = max3(z[15], z[16], z[17]);
    float b0 = max3(a0, a1, a2);
    float b1 = max3(a3, a4, a5);
    const float m = max3(b0, b1, z[18]);

#pragma unroll
    for (int c = 0; c < NCH; ++c) z[c] = __builtin_amdgcn_exp2f(z[c] - m);

    float s0 = z[0] + z[1],  s1 = z[2] + z[3];
    float s2 = z[4] + z[5],  s3 = z[6] + z[7];
    float s4 = z[8] + z[9],  s5 = z[10] + z[11];
    float s6 = z[12] + z[13], s7 = z[14] + z[15];
    float s8 = z[16] + z[17];
    s0 += s1; s2 += s3; s4 += s5; s6 += s7; s8 += z[18];
    s0 += s2; s4 += s6;
    s0 += s4;
    const float r = __builtin_amdgcn_rcpf(s0 + s8);

#pragma unroll
    for (int c = 0; c < NCH; ++c) acc[c] = fmaf(z[c], r, acc[c]);

    kk = kknext;
  }

  float* pout = out + (size_t)b_ * (NCH * HW) + hw;
#pragma unroll
  for (int c = 0; c < NCH; ++c) pout[c * HW] = acc[c] * 0.01f;
}

extern "C" void kernel_launch(void* const* d_in, const int* in_sizes, int n_in,
                              void* d_out, int out_size, void* d_ws, size_t ws_size,
                              hipStream_t stream) {
  const float* in = (const float*)d_in[0];
  float* out = (float*)d_out;
  HeteroscedasticSoftmax_kernel<<<2048, 256, 0, stream>>>(in, out);
}

// Round 6
// 2113.593 us; speedup vs baseline: 1.0021x; 1.0021x over previous
//
#include <hip/hip_runtime.h>
#include <stdint.h>

// HeteroscedasticSoftmax: out = mean_{s<100} softmax(logits + eps_s * exp(log_std), axis=C)
// eps reproduces jax.random.normal under the partitionable threefry scheme (verified):
//   key_s  = threefry2x32((0,1), (0, s))
//   bits_j = w0 ^ w1 of threefry2x32(key_s, (0, j)), j = flat element index
//   u from top 23 bits; eps = sqrt2*erfinv(u) (coeff-folded, log2-domain central poly)
//
// R7: AGPR-move elimination. History: R3 (occupancy 4->6.8 waves), R6 (phase-split
// mega-BB) both perf-neutral at identical counters -> issue-slot scheduling is NOT the
// limiter; revised model is sustained-clock throttle (m07 pure-FMA ubench = 65% of
// nominal peak => real VALU busy here ~82% at ~1.6GHz, not 55% at 2.4).
// Last falsifiable slack: VGPR_Count=52 can't hold the 57 persistent floats
// (lgE/sdE/acc) + threefry working set -> allocator parked arrays in AGPRs under the
// (256,4) 128-reg cap, paying v_accvgpr_read/write moves (~76 VALU/pixel-sample, ~4%).
//  - __launch_bounds__(256,3): ~168-reg budget, whole state in arch VGPRs, no moves.
//    (R2==R3 proved 4 vs 6.8 waves/SIMD is perf-neutral; 3 is enough for 4-8cy VALU dep.)
//  - Single fused per-channel loop (R5 shape; R6's split was compiler-reverted anyway,
//    and its u_/t_ arrays only added AGPR pressure: 2285 -> 2340).
//  - Kept: parallel chain init (x0,x1 independent adds off SALU consts), 1-deep skey
//    prefetch, v_alignbit bit-insert, SALU-folded key schedule, max3 tree.
// If VGPR jumps to ~100+ and duration stays ~2340 rocprof: declare roofline.

#define NCH    19
#define HW     65536
#define NSAMP  100

__device__ __forceinline__ uint32_t rotl(uint32_t x, uint32_t r) {
  return __builtin_amdgcn_alignbit(x, x, 32u - r);
}

__device__ __forceinline__ void tf2x32_full(uint32_t k0, uint32_t k1,
                                            uint32_t x0, uint32_t x1,
                                            uint32_t& o0, uint32_t& o1) {
  const uint32_t k2 = k0 ^ k1 ^ 0x1BD11BDAu;
#define TFR(r) { x0 += x1; x1 = rotl(x1, r) ^ x0; }
  x0 += k0; x1 += k1;
  TFR(13u) TFR(15u) TFR(26u) TFR(6u)
  x0 += k1; x1 += k2 + 1u;
  TFR(17u) TFR(29u) TFR(16u) TFR(24u)
  x0 += k2; x1 += k0 + 2u;
  TFR(13u) TFR(15u) TFR(26u) TFR(6u)
  x0 += k0; x1 += k1 + 3u;
  TFR(17u) TFR(29u) TFR(16u) TFR(24u)
  x0 += k1; x1 += k2 + 4u;
  TFR(13u) TFR(15u) TFR(26u) TFR(6u)
  x0 += k2; x1 += k0 + 5u;
#undef TFR
  o0 = x0; o1 = x1;
}

// Hot-path threefry given both initial regs (x0 = counter + k0 + k1-part,
// x1 = counter + k1-part; identical mod-2^32 arithmetic to the verified serial
// form x0 = k0 + x1). Keys wave-uniform (SGPR). Returns o0 ^ o1.
__device__ __forceinline__ uint32_t tf_fold_xy(uint32_t k0, uint32_t k1, uint32_t k2,
                                               uint32_t x0, uint32_t x1) {
  x1 = rotl(x1, 13u) ^ x0;
  x0 += x1; x1 = rotl(x1, 15u) ^ x0;
  x0 += x1; x1 = rotl(x1, 26u) ^ x0;
  x0 += x1; x1 = rotl(x1,  6u) ^ x0;
  x1 += k2 + 1u;
  x0 = x0 + k1 + x1; x1 = rotl(x1, 17u) ^ x0;
  x0 += x1; x1 = rotl(x1, 29u) ^ x0;
  x0 += x1; x1 = rotl(x1, 16u) ^ x0;
  x0 += x1; x1 = rotl(x1, 24u) ^ x0;
  x1 += k0 + 2u;
  x0 = x0 + k2 + x1; x1 = rotl(x1, 13u) ^ x0;
  x0 += x1; x1 = rotl(x1, 15u) ^ x0;
  x0 += x1; x1 = rotl(x1, 26u) ^ x0;
  x0 += x1; x1 = rotl(x1,  6u) ^ x0;
  x1 += k1 + 3u;
  x0 = x0 + k0 + x1; x1 = rotl(x1, 17u) ^ x0;
  x0 += x1; x1 = rotl(x1, 29u) ^ x0;
  x0 += x1; x1 = rotl(x1, 16u) ^ x0;
  x0 += x1; x1 = rotl(x1, 24u) ^ x0;
  x1 += k2 + 4u;
  x0 = x0 + k1 + x1; x1 = rotl(x1, 13u) ^ x0;
  x0 += x1; x1 = rotl(x1, 15u) ^ x0;
  x0 += x1; x1 = rotl(x1, 26u) ^ x0;
  x0 += x1; x1 = rotl(x1,  6u) ^ x0;
  return (x0 + k2) ^ (x1 + k0 + 5u);
}

// sqrt(2)*erfinv(u); central poly evaluated directly in t = log2(1-u^2)
// (alpha = -ln2 folded into coefficients; center beta = 2.5/alpha).
__device__ __forceinline__ float bits_to_eps(uint32_t bits) {
  // y = bitcast(0x40000000 | (bits>>9)) in [2,4) == 2x; one alignbit, no shift+or.
  float y = __uint_as_float(__builtin_amdgcn_alignbit(0x80u, bits, 9u));
  float u = y - 3.0f;                  // exact (Sterbenz); in [-1.0, 0.99999976]
  u = fmaxf(u, -0.99999994f);          // REQUIRED: u=-1.0 at bits>>9==0 -> log2(0) -> NaN
  float omu2 = fmaf(-u, u, 1.0f);      // 1 - u^2 >= ~1.19e-7 > 0
  float t = __builtin_amdgcn_logf(omu2);   // log2(1-u^2), <= 0
  float p;
  if (omu2 > 0.0067379470f) {   // == t > -7.2135401 (central, w = -ln2*t < 5)
    float tw = t + 3.6067376f;  // t - beta
    p = 2.1176667e-09f;
    p = fmaf(p, tw, -3.7319753e-08f);
    p = fmaf(p, tw, -5.5262077e-07f);
    p = fmaf(p, tw, 9.9370361e-07f);
    p = fmaf(p, tw, 7.1355918e-05f);
    p = fmaf(p, tw, 5.9046852e-04f);
    p = fmaf(p, tw, -2.8386612e-03f);
    p = fmaf(p, tw, -2.4177230e-01f);
    p = fmaf(p, tw, 2.1233141e+00f);
  } else {                      // tail (rare, ~0.34% of lanes): reconstruct w
    float w = -0.69314718f * t;
    w = __fsqrt_rn(w) - 3.0f;
    p = -2.8314594e-04f;
    p = fmaf(p, w, 1.4276565e-04f);
    p = fmaf(p, w, 1.9082604e-03f);
    p = fmaf(p, w, -5.1950124e-03f);
    p = fmaf(p, w, 8.1168916e-03f);
    p = fmaf(p, w, -1.0779791e-02f);
    p = fmaf(p, w, 1.3348577e-02f);
    p = fmaf(p, w, 1.4165810e+00f);
    p = fmaf(p, w, 4.0064324e+00f);
  }
  return p * u;
}

__device__ __forceinline__ float max3(float a, float b, float c) {
  return fmaxf(fmaxf(a, b), c);   // clang fuses to v_max3_f32
}

__global__ __launch_bounds__(256, 3)
void HeteroscedasticSoftmax_kernel(const float* __restrict__ in,
                                   float* __restrict__ out) {
  __shared__ uint2 skey[NSAMP];

  const int t = threadIdx.x;
  if (t < NSAMP) {
    uint32_t a, b;
    tf2x32_full(0u, 1u, 0u, (uint32_t)t, a, b);
    skey[t] = make_uint2(a, b);
  }

  const int gid = blockIdx.x * 256 + t;    // one pixel per thread
  const int b_  = gid >> 16;
  const int hw  = gid & 65535;

  const float L2E = 1.4426950408889634f;
  const float* pin = in + (size_t)b_ * (2 * NCH * HW) + hw;
  float lgE[NCH], sdE[NCH], acc[NCH];
#pragma unroll
  for (int c = 0; c < NCH; ++c) {
    const float lg = pin[c * HW];
    const float ls = pin[(NCH + c) * HW];
    lgE[c] = lg * L2E;
    sdE[c] = __expf(ls) * L2E;
    acc[c] = 0.0f;
  }
  __syncthreads();

  const uint32_t jbase = (uint32_t)(b_ * NCH) * (uint32_t)HW + (uint32_t)hw;

  uint2 kk = skey[0];   // after barrier; 1-deep prefetch below

#pragma unroll 1
  for (int s = 0; s < NSAMP; ++s) {
    const uint2 kknext = skey[(s + 1 < NSAMP) ? s + 1 : 0];  // consumed next iter
    const uint32_t k0 = __builtin_amdgcn_readfirstlane(kk.x);
    const uint32_t k1 = __builtin_amdgcn_readfirstlane(kk.y);
    const uint32_t k2 = k0 ^ k1 ^ 0x1BD11BDAu;

    float z[NCH];
#pragma unroll
    for (int c = 0; c < NCH; ++c) {
      const uint32_t k1c  = k1 + (uint32_t)(c * HW);   // SALU (wave-uniform)
      const uint32_t k01c = k0 + k1c;                  // SALU (wave-uniform)
      const uint32_t bits = tf_fold_xy(k0, k1, k2, jbase + k01c, jbase + k1c);
      const float eps = bits_to_eps(bits);
      z[c] = fmaf(eps, sdE[c], lgE[c]);   // (lg + eps*sd) * log2(e)
    }

    // 19-way max in triples: 9 v_max3_f32
    float a0 = max3(z[0],  z[1],  z[2]);
    float a1 = max3(z[3],  z[4],  z[5]);
    float a2 = max3(z[6],  z[7],  z[8]);
    float a3 = max3(z[9],  z[10], z[11]);
    float a4 = max3(z[12], z[13], z[14]);
    float a5 = max3(z[15], z[16], z[17]);
    float b0 = max3(a0, a1, a2);
    float b1 = max3(a3, a4, a5);
    const float m = max3(b0, b1, z[18]);

#pragma unroll
    for (int c = 0; c < NCH; ++c) z[c] = __builtin_amdgcn_exp2f(z[c] - m);

    float s0 = z[0] + z[1],  s1 = z[2] + z[3];
    float s2 = z[4] + z[5],  s3 = z[6] + z[7];
    float s4 = z[8] + z[9],  s5 = z[10] + z[11];
    float s6 = z[12] + z[13], s7 = z[14] + z[15];
    float s8 = z[16] + z[17];
    s0 += s1; s2 += s3; s4 += s5; s6 += s7; s8 += z[18];
    s0 += s2; s4 += s6;
    s0 += s4;
    const float r = __builtin_amdgcn_rcpf(s0 + s8);

#pragma unroll
    for (int c = 0; c < NCH; ++c) acc[c] = fmaf(z[c], r, acc[c]);

    kk = kknext;
  }

  float* pout = out + (size_t)b_ * (NCH * HW) + hw;
#pragma unroll
  for (int c = 0; c < NCH; ++c) pout[c * HW] = acc[c] * 0.01f;
}

extern "C" void kernel_launch(void* const* d_in, const int* in_sizes, int n_in,
                              void* d_out, int out_size, void* d_ws, size_t ws_size,
                              hipStream_t stream) {
  const float* in = (const float*)d_in[0];
  float* out = (float*)d_out;
  HeteroscedasticSoftmax_kernel<<<2048, 256, 0, stream>>>(in, out);
}